// Round 1
// baseline (115.055 us; speedup 1.0000x reference)
//
#include <hip/hip_runtime.h>
#include <hip/hip_bf16.h>

// out[s,d] = (sum_{t in seg s} log1p(inten[t]) * emb[t,d] + W0*offset[d])
//            / (sum_{t in seg s} log1p(inten[t]) + W0)
// segment_ids sorted -> contiguous ranges. Two kernels:
//  1) boundary scan -> starts[B+1] in d_ws
//  2) one wave per segment, float4-vectorized, butterfly reduce.

#define W0 0.69314718055994530942f  // log1p(1.0)

__global__ void seg_bounds_kernel(const int* __restrict__ ids,
                                  int* __restrict__ starts,
                                  int T, int B) {
    int t = blockIdx.x * blockDim.x + threadIdx.x;
    if (t >= T) return;
    int cur  = ids[t];
    int prev = (t == 0) ? -1 : ids[t - 1];
    // starts[s] = first token index with id >= s, for s in (prev, cur]
    for (int s = prev + 1; s <= cur; ++s) starts[s] = t;
    if (t == T - 1) {
        // trailing (possibly empty) segments + sentinel
        for (int s = cur + 1; s <= B; ++s) starts[s] = T;
    }
}

__global__ void __launch_bounds__(256)
seg_embed_kernel(const float* __restrict__ emb,
                 const float* __restrict__ inten,
                 const int*   __restrict__ starts,
                 const float* __restrict__ offset_tok,
                 float* __restrict__ out,
                 int B) {
    const int gtid = blockIdx.x * blockDim.x + threadIdx.x;
    const int seg  = gtid >> 6;          // one wave (64 lanes) per segment
    if (seg >= B) return;
    const int lane = threadIdx.x & 63;
    const int tgrp = lane >> 4;          // token subgroup 0..3
    const int dq   = lane & 15;          // dim quad: dims [dq*4, dq*4+3]

    const int t0 = starts[seg];
    const int t1 = starts[seg + 1];

    float4 acc = make_float4(0.f, 0.f, 0.f, 0.f);
    float  wsum = 0.f;

    for (int t = t0; t < t1; t += 4) {
        const int tt = t + tgrp;
        if (tt < t1) {
            const float w = __logf(1.0f + inten[tt]);  // log1p, x in [0,1)
            const float4 e = *reinterpret_cast<const float4*>(
                emb + (size_t)tt * 64 + dq * 4);
            acc.x = fmaf(e.x, w, acc.x);
            acc.y = fmaf(e.y, w, acc.y);
            acc.z = fmaf(e.z, w, acc.z);
            acc.w = fmaf(e.w, w, acc.w);
            wsum += w;
        }
    }

    // butterfly reduce across the 4 token subgroups (bits 4 and 5 of lane).
    // dim quad (lane&15) is preserved by xor 16 / xor 32.
    acc.x += __shfl_xor(acc.x, 16); acc.y += __shfl_xor(acc.y, 16);
    acc.z += __shfl_xor(acc.z, 16); acc.w += __shfl_xor(acc.w, 16);
    wsum  += __shfl_xor(wsum, 16);
    acc.x += __shfl_xor(acc.x, 32); acc.y += __shfl_xor(acc.y, 32);
    acc.z += __shfl_xor(acc.z, 32); acc.w += __shfl_xor(acc.w, 32);
    wsum  += __shfl_xor(wsum, 32);

    if (lane < 16) {
        const float4 off = *reinterpret_cast<const float4*>(offset_tok + dq * 4);
        const float inv = 1.0f / (wsum + W0);
        float4 r;
        r.x = (acc.x + W0 * off.x) * inv;
        r.y = (acc.y + W0 * off.y) * inv;
        r.z = (acc.z + W0 * off.z) * inv;
        r.w = (acc.w + W0 * off.w) * inv;
        *reinterpret_cast<float4*>(out + (size_t)seg * 64 + dq * 4) = r;
    }
}

extern "C" void kernel_launch(void* const* d_in, const int* in_sizes, int n_in,
                              void* d_out, int out_size, void* d_ws, size_t ws_size,
                              hipStream_t stream) {
    const float* emb        = (const float*)d_in[0];
    const float* inten      = (const float*)d_in[1];
    const int*   ids        = (const int*)d_in[2];
    const float* offset_tok = (const float*)d_in[3];
    float*       out        = (float*)d_out;

    const int T = in_sizes[1];       // TOTAL_TOKENS
    const int B = out_size / 64;     // NUM_SEGMENTS (D = 64)

    int* starts = (int*)d_ws;        // B+1 ints

    {
        const int block = 256;
        const int grid  = (T + block - 1) / block;
        seg_bounds_kernel<<<grid, block, 0, stream>>>(ids, starts, T, B);
    }
    {
        const int block = 256;                       // 4 waves/block
        const int grid  = (B * 64 + block - 1) / block;
        seg_embed_kernel<<<grid, block, 0, stream>>>(emb, inten, starts,
                                                     offset_tok, out, B);
    }
}

// Round 2
// 98.296 us; speedup vs baseline: 1.1705x; 1.1705x over previous
//
#include <hip/hip_runtime.h>
#include <hip/hip_bf16.h>

// out[s,d] = (sum_{t in seg s} log1p(inten[t]) * emb[t,d] + W0*offset[d])
//            / (sum_{t in seg s} log1p(inten[t]) + W0)
// segment_ids sorted -> contiguous ranges. Two kernels:
//  1) boundary scan -> starts[B+1] in d_ws
//  2) one wave per segment; 4 token-subgroups x 16 dim-quads; 8 tokens/iter
//     main loop (unconditional, 2 float4 streams in flight), butterfly reduce.

#define W0 0.69314718055994530942f  // log1p(1.0)

typedef float f32x4 __attribute__((ext_vector_type(4)));

__global__ void seg_bounds_kernel(const int* __restrict__ ids,
                                  int* __restrict__ starts,
                                  int T, int B) {
    int t = blockIdx.x * blockDim.x + threadIdx.x;
    if (t >= T) return;
    int cur  = ids[t];
    int prev = (t == 0) ? -1 : ids[t - 1];
    for (int s = prev + 1; s <= cur; ++s) starts[s] = t;
    if (t == T - 1) {
        for (int s = cur + 1; s <= B; ++s) starts[s] = T;
    }
}

__global__ void __launch_bounds__(256)
seg_embed_kernel(const float* __restrict__ emb,
                 const float* __restrict__ inten,
                 const int*   __restrict__ starts,
                 const float* __restrict__ offset_tok,
                 float* __restrict__ out,
                 int B) {
    const int gtid = blockIdx.x * blockDim.x + threadIdx.x;
    const int seg  = gtid >> 6;          // one wave (64 lanes) per segment
    if (seg >= B) return;
    const int lane = threadIdx.x & 63;
    const int tgrp = lane >> 4;          // token subgroup 0..3
    const int dq   = lane & 15;          // dim quad: dims [dq*4, dq*4+3]

    const int t0 = starts[seg];
    const int t1 = starts[seg + 1];

    f32x4 acc0 = {0.f, 0.f, 0.f, 0.f};
    f32x4 acc1 = {0.f, 0.f, 0.f, 0.f};
    float wsum0 = 0.f, wsum1 = 0.f;

    int t = t0;
    // main loop: 8 tokens per trip, two independent load streams
    for (; t + 8 <= t1; t += 8) {
        const int ta = t + tgrp;
        const int tb = t + 4 + tgrp;
        const float ia = inten[ta];
        const float ib = inten[tb];
        const f32x4 ea = __builtin_nontemporal_load(
            reinterpret_cast<const f32x4*>(emb + (size_t)ta * 64 + dq * 4));
        const f32x4 eb = __builtin_nontemporal_load(
            reinterpret_cast<const f32x4*>(emb + (size_t)tb * 64 + dq * 4));
        const float wa = __logf(1.0f + ia);
        const float wb = __logf(1.0f + ib);
        acc0[0] = fmaf(ea[0], wa, acc0[0]);
        acc0[1] = fmaf(ea[1], wa, acc0[1]);
        acc0[2] = fmaf(ea[2], wa, acc0[2]);
        acc0[3] = fmaf(ea[3], wa, acc0[3]);
        wsum0 += wa;
        acc1[0] = fmaf(eb[0], wb, acc1[0]);
        acc1[1] = fmaf(eb[1], wb, acc1[1]);
        acc1[2] = fmaf(eb[2], wb, acc1[2]);
        acc1[3] = fmaf(eb[3], wb, acc1[3]);
        wsum1 += wb;
    }
    // one full 4-token group
    if (t + 4 <= t1) {
        const int ta = t + tgrp;
        const float ia = inten[ta];
        const f32x4 ea = __builtin_nontemporal_load(
            reinterpret_cast<const f32x4*>(emb + (size_t)ta * 64 + dq * 4));
        const float wa = __logf(1.0f + ia);
        acc0[0] = fmaf(ea[0], wa, acc0[0]);
        acc0[1] = fmaf(ea[1], wa, acc0[1]);
        acc0[2] = fmaf(ea[2], wa, acc0[2]);
        acc0[3] = fmaf(ea[3], wa, acc0[3]);
        wsum0 += wa;
        t += 4;
    }
    // masked tail (< 4 tokens)
    if (t + tgrp < t1) {
        const int ta = t + tgrp;
        const float ia = inten[ta];
        const f32x4 ea = *reinterpret_cast<const f32x4*>(
            emb + (size_t)ta * 64 + dq * 4);
        const float wa = __logf(1.0f + ia);
        acc1[0] = fmaf(ea[0], wa, acc1[0]);
        acc1[1] = fmaf(ea[1], wa, acc1[1]);
        acc1[2] = fmaf(ea[2], wa, acc1[2]);
        acc1[3] = fmaf(ea[3], wa, acc1[3]);
        wsum1 += wa;
    }

    f32x4 acc;
    acc[0] = acc0[0] + acc1[0];
    acc[1] = acc0[1] + acc1[1];
    acc[2] = acc0[2] + acc1[2];
    acc[3] = acc0[3] + acc1[3];
    float wsum = wsum0 + wsum1;

    // butterfly reduce across the 4 token subgroups (bits 4 and 5 of lane).
    acc[0] += __shfl_xor(acc[0], 16); acc[1] += __shfl_xor(acc[1], 16);
    acc[2] += __shfl_xor(acc[2], 16); acc[3] += __shfl_xor(acc[3], 16);
    wsum   += __shfl_xor(wsum, 16);
    acc[0] += __shfl_xor(acc[0], 32); acc[1] += __shfl_xor(acc[1], 32);
    acc[2] += __shfl_xor(acc[2], 32); acc[3] += __shfl_xor(acc[3], 32);
    wsum   += __shfl_xor(wsum, 32);

    if (lane < 16) {
        const f32x4 off = *reinterpret_cast<const f32x4*>(offset_tok + dq * 4);
        const float inv = 1.0f / (wsum + W0);
        f32x4 r;
        r[0] = (acc[0] + W0 * off[0]) * inv;
        r[1] = (acc[1] + W0 * off[1]) * inv;
        r[2] = (acc[2] + W0 * off[2]) * inv;
        r[3] = (acc[3] + W0 * off[3]) * inv;
        *reinterpret_cast<f32x4*>(out + (size_t)seg * 64 + dq * 4) = r;
    }
}

extern "C" void kernel_launch(void* const* d_in, const int* in_sizes, int n_in,
                              void* d_out, int out_size, void* d_ws, size_t ws_size,
                              hipStream_t stream) {
    const float* emb        = (const float*)d_in[0];
    const float* inten      = (const float*)d_in[1];
    const int*   ids        = (const int*)d_in[2];
    const float* offset_tok = (const float*)d_in[3];
    float*       out        = (float*)d_out;

    const int T = in_sizes[1];       // TOTAL_TOKENS
    const int B = out_size / 64;     // NUM_SEGMENTS (D = 64)

    int* starts = (int*)d_ws;        // B+1 ints

    {
        const int block = 256;
        const int grid  = (T + block - 1) / block;
        seg_bounds_kernel<<<grid, block, 0, stream>>>(ids, starts, T, B);
    }
    {
        const int block = 256;                       // 4 waves/block
        const int grid  = (B * 64 + block - 1) / block;
        seg_embed_kernel<<<grid, block, 0, stream>>>(emb, inten, starts,
                                                     offset_tok, out, B);
    }
}